// Round 2
// baseline (1553.164 us; speedup 1.0000x reference)
//
#include <hip/hip_runtime.h>
#include <hip/hip_bf16.h>

// Problem constants (SymNetDP): B=64, S=4096, NGB=13, NG=48, DIM=3, NCH={8,8,1}
#define BATCH 64
#define SITES 4096
#define NGB 13
#define NGRP 48
#define SDIM 3

// ---------------------------------------------------------------------------
// Workspace layout (floats):
//   GW0 : (8,48,13)     =  4992   @ 0
//   GW1 : (8,48,104)    = 39936   @ 4992
//   GW2 : (48,104)      =  4992   @ 44928
//   Avc : (3,13)        =    39   @ 49920  (padded to 49984)
//   A0  : (B,8,S)       = 2097152 @ 49984
//   A1  : (B,8,S)       = 2097152 @ 2147136
//   A2  : (B,1,S)       =  262144 @ 4244288
// ---------------------------------------------------------------------------
#define OFF_GW0 0
#define OFF_GW1 4992
#define OFF_GW2 44928
#define OFF_AVC 49920
#define OFF_A0  49984
#define OFF_A1  2147136
#define OFF_A2  4244288

__device__ __forceinline__ float softplus_f(float h) {
    // stable: max(h,0) + log(1+exp(-|h|))
    return fmaxf(h, 0.f) + __logf(1.f + __expf(-fabsf(h)));
}

// ---------------------------------------------------------------------------
// Precompute: rotated weights GW0/GW1/GW2 and the collapsed vector-channel
// matrix Avc[d,n] = (1/48) * sum_g (gdiags @ P)[g*3+d, n]
// ---------------------------------------------------------------------------
__global__ __launch_bounds__(256) void precompute_kernel(
    const float* __restrict__ Psi0, const float* __restrict__ Psi1,
    const float* __restrict__ Psi2, const float* __restrict__ wtVC,
    const float* __restrict__ gdiags, const int* __restrict__ perms,
    float* __restrict__ ws)
{
    float* GW0 = ws + OFF_GW0;
    float* GW1 = ws + OFF_GW1;
    float* GW2 = ws + OFF_GW2;
    float* Avc = ws + OFF_AVC;
    int t = blockIdx.x * 256 + threadIdx.x;
    if (t < 4992) {
        // GW0[o][g][j] = Psi0[o, 0, perm[g,j]]
        int j = t % NGB; int og = t / NGB; int g = og % NGRP; int o = og / NGRP;
        GW0[t] = Psi0[o * NGB + perms[g * NGB + j]];
    } else if (t < 44928) {
        int u = t - 4992;
        // GW1[o][g][c*13+j] = Psi1[o, c, perm[g,j]]
        int k = u % 104; int og = u / 104; int g = og % NGRP; int o = og / NGRP;
        int c = k / NGB; int j = k % NGB;
        GW1[u] = Psi1[(o * 8 + c) * NGB + perms[g * NGB + j]];
    } else if (t < 49920) {
        int u = t - 44928;
        // GW2[g][c*13+j] = Psi2[0, c, perm[g,j]]
        int k = u % 104; int g = u / 104; int c = k / NGB; int j = k % NGB;
        GW2[u] = Psi2[c * NGB + perms[g * NGB + j]];
    } else if (t < 49959) {
        int u = t - 49920;          // u = d*13 + n
        int d = u / NGB, n = u % NGB;
        float s = 0.f;
        for (int g = 0; g < NGRP; g++) {
            int row = g * SDIM + d;
            for (int k = 0; k < NGRP * SDIM; k++) {
                int g2 = k / SDIM, d2 = k % SDIM;
                float p = wtVC[d2 * NGB + perms[g2 * NGB + n]];
                s = fmaf(gdiags[row * (NGRP * SDIM) + k], p, s);
            }
        }
        Avc[u] = s * (1.f / 48.f);
    }
}

// ---------------------------------------------------------------------------
// One gconv layer. Thread = one (b,s) column, x in VGPRs.
// Weights are read with BLOCK-UNIFORM indices from global -> compiler
// scalarizes to s_load + v_fmac with SGPR operand (no LDS, no per-lane VMEM).
// 8 independent h-accumulators (one per group in the block) hide FMA latency.
// Numerics: per-h chain is ascending-k; acc adds softplus terms in ascending
// g order -> identical rounding to the round-1 passing kernel.
// ---------------------------------------------------------------------------
template<int NCIN, int NCOUT>
__global__ __launch_bounds__(256) void layer_kernel(
    const float* __restrict__ prev,   // (B, NCIN, S)
    const float* __restrict__ GW,     // (NCOUT, 48, NCIN*13)
    const float* __restrict__ bias,   // (NCOUT, 1)
    const int*   __restrict__ NN,     // (13, S)
    float* __restrict__ out)          // (B, NCOUT, S)
{
    constexpr int K = NCIN * NGB;
    constexpr int GB = 8;             // groups in flight

    const int tid = threadIdx.x;
    const int b = blockIdx.x >> 4;                 // S/256 = 16 chunks per b
    const int s = ((blockIdx.x & 15) << 8) + tid;

    int nn[NGB];
#pragma unroll
    for (int j = 0; j < NGB; j++) nn[j] = NN[j * SITES + s];

    float x[K];
#pragma unroll
    for (int c = 0; c < NCIN; c++) {
        const float* p = prev + (size_t)(b * NCIN + c) * SITES;
#pragma unroll
        for (int j = 0; j < NGB; j++) x[c * NGB + j] = p[nn[j]];
    }

#pragma unroll 1
    for (int o = 0; o < NCOUT; o++) {
        const float bo = bias[o];
        float acc = 0.f;
#pragma unroll 1
        for (int g0 = 0; g0 < NGRP; g0 += GB) {
            const float* w = GW + ((size_t)o * NGRP + g0) * K;  // uniform
            float h[GB];
#pragma unroll
            for (int gi = 0; gi < GB; gi++) h[gi] = bo;
#pragma unroll
            for (int k = 0; k < K; k++) {
                const float xv = x[k];
#pragma unroll
                for (int gi = 0; gi < GB; gi++)
                    h[gi] = fmaf(w[gi * K + k], xv, h[gi]);
            }
#pragma unroll
            for (int gi = 0; gi < GB; gi++) acc += softplus_f(h[gi]);
        }
        out[((size_t)(b * NCOUT) + o) * SITES + s] = acc * (1.f / 48.f);
    }
}

// ---------------------------------------------------------------------------
// Final: out[b,d] = (1/S) * sum_s sw[shell[s]] * sum_n Avc[d,n]*A2[b,NN[n,s]]
// ---------------------------------------------------------------------------
__global__ __launch_bounds__(256) void reduce_kernel(
    const float* __restrict__ A2,     // (B, S)
    const int*   __restrict__ NN,     // (13, S)
    const int*   __restrict__ s2sh,   // (S,)
    const float* __restrict__ sw,     // (NSHELLS,)
    const float* __restrict__ Avc,    // (3, 13)
    float* __restrict__ out)          // (B, 3)
{
    const int b = blockIdx.x;
    const int tid = threadIdx.x;
    const float* a = A2 + (size_t)b * SITES;

    float A0r[NGB], A1r[NGB], A2r[NGB];
#pragma unroll
    for (int n = 0; n < NGB; n++) {
        A0r[n] = Avc[n];
        A1r[n] = Avc[NGB + n];
        A2r[n] = Avc[2 * NGB + n];
    }

    float acc0 = 0.f, acc1 = 0.f, acc2 = 0.f;
    for (int s = tid; s < SITES; s += 256) {
        float y0 = 0.f, y1 = 0.f, y2 = 0.f;
#pragma unroll
        for (int n = 0; n < NGB; n++) {
            float v = a[NN[n * SITES + s]];
            y0 = fmaf(A0r[n], v, y0);
            y1 = fmaf(A1r[n], v, y1);
            y2 = fmaf(A2r[n], v, y2);
        }
        float wgt = sw[s2sh[s]];
        acc0 = fmaf(wgt, y0, acc0);
        acc1 = fmaf(wgt, y1, acc1);
        acc2 = fmaf(wgt, y2, acc2);
    }

    __shared__ float red[3][256];
    red[0][tid] = acc0; red[1][tid] = acc1; red[2][tid] = acc2;
    __syncthreads();
    for (int st = 128; st > 0; st >>= 1) {
        if (tid < st) {
            red[0][tid] += red[0][tid + st];
            red[1][tid] += red[1][tid + st];
            red[2][tid] += red[2][tid + st];
        }
        __syncthreads();
    }
    if (tid == 0) {
        out[b * 3 + 0] = red[0][0] * (1.f / (float)SITES);
        out[b * 3 + 1] = red[1][0] * (1.f / (float)SITES);
        out[b * 3 + 2] = red[2][0] * (1.f / (float)SITES);
    }
}

// ---------------------------------------------------------------------------
extern "C" void kernel_launch(void* const* d_in, const int* in_sizes, int n_in,
                              void* d_out, int out_size, void* d_ws, size_t ws_size,
                              hipStream_t stream)
{
    const float* InStates = (const float*)d_in[0];   // (64,1,4096)
    const float* Psi0     = (const float*)d_in[1];   // (8,1,13)
    const float* bias0    = (const float*)d_in[2];   // (8,1)
    const float* Psi1     = (const float*)d_in[3];   // (8,8,13)
    const float* bias1    = (const float*)d_in[4];   // (8,1)
    const float* Psi2     = (const float*)d_in[5];   // (1,8,13)
    const float* bias2    = (const float*)d_in[6];   // (1,1)
    const float* wtVC     = (const float*)d_in[7];   // (3,13)
    const float* ShellW   = (const float*)d_in[8];   // (8,)
    const float* gdiags   = (const float*)d_in[9];   // (144,144)
    const int*   GnnPerms = (const int*)d_in[10];    // (48,13)
    const int*   NNSites  = (const int*)d_in[11];    // (13,4096)
    const int*   S2Sh     = (const int*)d_in[12];    // (4096,)

    float* ws  = (float*)d_ws;
    float* GW0 = ws + OFF_GW0;
    float* GW1 = ws + OFF_GW1;
    float* GW2 = ws + OFF_GW2;
    float* Avc = ws + OFF_AVC;
    float* A0  = ws + OFF_A0;
    float* A1  = ws + OFF_A1;
    float* A2  = ws + OFF_A2;

    float* out = (float*)d_out;  // (64,3) f32

    precompute_kernel<<<196, 256, 0, stream>>>(Psi0, Psi1, Psi2, wtVC, gdiags,
                                               GnnPerms, ws);

    layer_kernel<1, 8><<<1024, 256, 0, stream>>>(InStates, GW0, bias0, NNSites, A0);
    layer_kernel<8, 8><<<1024, 256, 0, stream>>>(A0,       GW1, bias1, NNSites, A1);
    layer_kernel<8, 1><<<1024, 256, 0, stream>>>(A1,       GW2, bias2, NNSites, A2);

    reduce_kernel<<<BATCH, 256, 0, stream>>>(A2, NNSites, S2Sh, ShellW, Avc, out);
}

// Round 3
// 1496.270 us; speedup vs baseline: 1.0380x; 1.0380x over previous
//
#include <hip/hip_runtime.h>
#include <hip/hip_bf16.h>

// Problem constants (SymNetDP): B=64, S=4096, NGB=13, NG=48, DIM=3, NCH={8,8,1}
#define BATCH 64
#define SITES 4096
#define NGB 13
#define NGRP 48
#define SDIM 3

// ---------------------------------------------------------------------------
// Workspace layout (floats):
//   GW0 : (8,48,13)     =  4992   @ 0
//   GW1 : (8,48,104)    = 39936   @ 4992
//   GW2 : (48,104)      =  4992   @ 44928
//   Avc : (3,13)        =    39   @ 49920  (padded to 49984)
//   A0  : (B,8,S)       = 2097152 @ 49984
//   A1  : (B,8,S)       = 2097152 @ 2147136
//   A2  : (B,1,S)       =  262144 @ 4244288
//   PART: (64,16,3)     =  3072   @ 4506432
// ---------------------------------------------------------------------------
#define OFF_GW0 0
#define OFF_GW1 4992
#define OFF_GW2 44928
#define OFF_AVC 49920
#define OFF_A0  49984
#define OFF_A1  2147136
#define OFF_A2  4244288
#define OFF_PART 4506432

__device__ __forceinline__ float softplus_f(float h) {
    // stable: max(h,0) + log(1+exp(-|h|))
    return fmaxf(h, 0.f) + __logf(1.f + __expf(-fabsf(h)));
}

// ---------------------------------------------------------------------------
// Precompute: rotated weights GW0/GW1/GW2; Avc via per-(d,n,g) threads with
// atomicAdd (Avc zeroed by hipMemsetAsync before this kernel).
// ---------------------------------------------------------------------------
__global__ __launch_bounds__(256) void precompute_kernel(
    const float* __restrict__ Psi0, const float* __restrict__ Psi1,
    const float* __restrict__ Psi2, const float* __restrict__ wtVC,
    const float* __restrict__ gdiags, const int* __restrict__ perms,
    float* __restrict__ ws)
{
    float* GW0 = ws + OFF_GW0;
    float* GW1 = ws + OFF_GW1;
    float* GW2 = ws + OFF_GW2;
    float* Avc = ws + OFF_AVC;
    int t = blockIdx.x * 256 + threadIdx.x;
    if (t < 4992) {
        // GW0[o][g][j] = Psi0[o, 0, perm[g,j]]
        int j = t % NGB; int og = t / NGB; int g = og % NGRP; int o = og / NGRP;
        GW0[t] = Psi0[o * NGB + perms[g * NGB + j]];
    } else if (t < 44928) {
        int u = t - 4992;
        // GW1[o][g][c*13+j] = Psi1[o, c, perm[g,j]]
        int k = u % 104; int og = u / 104; int g = og % NGRP; int o = og / NGRP;
        int c = k / NGB; int j = k % NGB;
        GW1[u] = Psi1[(o * 8 + c) * NGB + perms[g * NGB + j]];
    } else if (t < 49920) {
        int u = t - 44928;
        // GW2[g][c*13+j] = Psi2[0, c, perm[g,j]]
        int k = u % 104; int g = u / 104; int c = k / NGB; int j = k % NGB;
        GW2[u] = Psi2[c * NGB + perms[g * NGB + j]];
    } else if (t < 49920 + 39 * NGRP) {
        int t2 = t - 49920;            // t2 = u*48 + g
        int g = t2 % NGRP, u = t2 / NGRP;
        int d = u / NGB, n = u % NGB;
        // Avc[d,n] += (1/48) * sum_k gdiags[g*3+d, k] * P[k, n]
        //   with P[g2*3+d2, n] = wtVC[d2, perm[g2, n]]
        const int row = g * SDIM + d;
        float s = 0.f;
        for (int k = 0; k < NGRP * SDIM; k++) {
            int g2 = k / SDIM, d2 = k - g2 * SDIM;
            float p = wtVC[d2 * NGB + perms[g2 * NGB + n]];
            s = fmaf(gdiags[row * (NGRP * SDIM) + k], p, s);
        }
        atomicAdd(&Avc[u], s * (1.f / 48.f));
    }
}

// ---------------------------------------------------------------------------
// Register-tiled gconv layer.
// Block = 256 threads tiling (OG x CT): thread owns TO og-pairs x TC columns.
// LDS: nn-tile, x-tile gathered+transposed [k][col], w chunk transposed
// [j][og] (+4 pad), restaged per input channel. Per k-step: TO+TC LDS floats
// feed TO*TC FMAs. Epilogue: softplus + group-mean via LDS partials.
// ---------------------------------------------------------------------------
template<int NCIN, int NCOUT, int TO, int GOG, int TC, int GCOL, int CT>
__global__ __launch_bounds__(256, 3) void layer_tiled(
    const float* __restrict__ prev,   // (B, NCIN, S)
    const float* __restrict__ GW,     // (NCOUT*48, NCIN*13) row-major
    const float* __restrict__ bias,   // (NCOUT,)
    const int*   __restrict__ NN,     // (13, S)
    float* __restrict__ out)          // (B, NCOUT, S)
{
    constexpr int OG   = NCOUT * NGRP;     // total (o,g) pairs
    constexpr int K    = NCIN * NGB;
    constexpr int WSTR = OG + 4;           // padded stride for w rows (banks)
    constexpr int PSTR = CT + 1;           // padded stride for partials
    constexpr int WSZ  = (NGB * WSTR > GOG * PSTR) ? NGB * WSTR : GOG * PSTR;
    constexpr int GPO  = NGRP / TO;        // og-groups per output channel

    static_assert(GOG * GCOL == 256, "");
    static_assert(TO * GOG == OG, "");
    static_assert(TC * GCOL == CT, "");
    static_assert(NGRP % TO == 0, "");     // thread's og range stays in one o

    __shared__ int   nn_lds[NGB * CT];
    __shared__ float x_lds[K * CT];        // [k][col]
    __shared__ float w_lds[WSZ];           // [j][og] chunk; reused for partials

    const int tid = threadIdx.x;
    const int og_group  = tid % GOG;
    const int col_group = tid / GOG;
    const int og0  = og_group * TO;
    const int col0 = col_group * TC;

    const int b  = blockIdx.x / (SITES / CT);
    const int s0 = (blockIdx.x % (SITES / CT)) * CT;

    // --- stage nn tile -----------------------------------------------------
    for (int e = tid; e < NGB * CT; e += 256) {
        int j = e / CT, col = e - j * CT;
        nn_lds[e] = NN[j * SITES + s0 + col];
    }
    __syncthreads();
    // --- stage gathered x tile, transposed [k][col] ------------------------
    for (int e = tid; e < K * CT; e += 256) {
        int k = e / CT, col = e - k * CT;
        int c = k / NGB, j = k - c * NGB;
        x_lds[e] = prev[((size_t)b * NCIN + c) * SITES + nn_lds[j * CT + col]];
    }

    const int o_base = og0 / NGRP;
    const float bo = bias[o_base];
    float h[TO][TC];
#pragma unroll
    for (int i = 0; i < TO; i++)
#pragma unroll
        for (int q = 0; q < TC; q++) h[i][q] = bo;

    // --- K loop in channel chunks of 13 ------------------------------------
#pragma unroll 1
    for (int c = 0; c < NCIN; c++) {
        __syncthreads();   // (also covers x/nn staging before first compute)
        // stage w chunk: GW[og][c*13+j] -> w_lds[j*WSTR + og]
        for (int e = tid; e < OG * NGB; e += 256) {
            int og = e / NGB, j = e - og * NGB;
            w_lds[j * WSTR + og] = GW[(size_t)og * K + c * NGB + j];
        }
        __syncthreads();
        const float* xc = &x_lds[c * NGB * CT];
#pragma unroll
        for (int j = 0; j < NGB; j++) {
            float wv[TO], xv[TC];
#pragma unroll
            for (int i = 0; i < TO; i++) wv[i] = w_lds[j * WSTR + og0 + i];
#pragma unroll
            for (int q = 0; q < TC; q++) xv[q] = xc[j * CT + col0 + q];
#pragma unroll
            for (int i = 0; i < TO; i++)
#pragma unroll
                for (int q = 0; q < TC; q++)
                    h[i][q] = fmaf(wv[i], xv[q], h[i][q]);
        }
    }

    // --- epilogue: softplus, partial og-sum, group-mean --------------------
    float sp[TC];
#pragma unroll
    for (int q = 0; q < TC; q++) {
        float s = 0.f;
#pragma unroll
        for (int i = 0; i < TO; i++) s += softplus_f(h[i][q]);
        sp[q] = s;
    }
    __syncthreads();                        // done reading w_lds as weights
    float* part = w_lds;                    // [og_group][PSTR]
#pragma unroll
    for (int q = 0; q < TC; q++) part[og_group * PSTR + col0 + q] = sp[q];
    __syncthreads();
    for (int e = tid; e < NCOUT * CT; e += 256) {
        int oo = e / CT, col = e - oo * CT;
        float s = 0.f;
#pragma unroll
        for (int r = 0; r < GPO; r++) s += part[(oo * GPO + r) * PSTR + col];
        out[((size_t)b * NCOUT + oo) * SITES + s0 + col] = s * (1.f / 48.f);
    }
}

// ---------------------------------------------------------------------------
// Reduce stage A: per (b, s-chunk) block -> 3 partial sums
// ---------------------------------------------------------------------------
__global__ __launch_bounds__(256) void reduce_a(
    const float* __restrict__ A2,     // (B, S)
    const int*   __restrict__ NN,     // (13, S)
    const int*   __restrict__ s2sh,   // (S,)
    const float* __restrict__ sw,     // (NSHELLS,)
    const float* __restrict__ Avc,    // (3, 13)
    float* __restrict__ partial)      // (B, 16, 3)
{
    const int b = blockIdx.x >> 4;
    const int chunk = blockIdx.x & 15;
    const int tid = threadIdx.x;
    const int s = (chunk << 8) + tid;
    const float* a = A2 + (size_t)b * SITES;

    float y0 = 0.f, y1 = 0.f, y2 = 0.f;
#pragma unroll
    for (int n = 0; n < NGB; n++) {
        float v = a[NN[n * SITES + s]];
        y0 = fmaf(Avc[n],           v, y0);
        y1 = fmaf(Avc[NGB + n],     v, y1);
        y2 = fmaf(Avc[2 * NGB + n], v, y2);
    }
    const float wgt = sw[s2sh[s]];
    y0 *= wgt; y1 *= wgt; y2 *= wgt;

    __shared__ float red[3][256];
    red[0][tid] = y0; red[1][tid] = y1; red[2][tid] = y2;
    __syncthreads();
    for (int st = 128; st > 0; st >>= 1) {
        if (tid < st) {
            red[0][tid] += red[0][tid + st];
            red[1][tid] += red[1][tid + st];
            red[2][tid] += red[2][tid + st];
        }
        __syncthreads();
    }
    if (tid < 3) partial[(b * 16 + chunk) * 3 + tid] = red[tid][0];
}

// ---------------------------------------------------------------------------
// Reduce stage B: deterministic combine of 16 chunk partials per (b,d)
// ---------------------------------------------------------------------------
__global__ __launch_bounds__(256) void reduce_b(
    const float* __restrict__ partial, float* __restrict__ out)
{
    int t = threadIdx.x;
    if (t < BATCH * 3) {
        int b = t / 3, d = t - b * 3;
        float s = 0.f;
        for (int c = 0; c < 16; c++) s += partial[(b * 16 + c) * 3 + d];
        out[t] = s * (1.f / (float)SITES);
    }
}

// ---------------------------------------------------------------------------
extern "C" void kernel_launch(void* const* d_in, const int* in_sizes, int n_in,
                              void* d_out, int out_size, void* d_ws, size_t ws_size,
                              hipStream_t stream)
{
    const float* InStates = (const float*)d_in[0];   // (64,1,4096)
    const float* Psi0     = (const float*)d_in[1];   // (8,1,13)
    const float* bias0    = (const float*)d_in[2];   // (8,1)
    const float* Psi1     = (const float*)d_in[3];   // (8,8,13)
    const float* bias1    = (const float*)d_in[4];   // (8,1)
    const float* Psi2     = (const float*)d_in[5];   // (1,8,13)
    const float* bias2    = (const float*)d_in[6];   // (1,1)
    const float* wtVC     = (const float*)d_in[7];   // (3,13)
    const float* ShellW   = (const float*)d_in[8];   // (8,)
    const float* gdiags   = (const float*)d_in[9];   // (144,144)
    const int*   GnnPerms = (const int*)d_in[10];    // (48,13)
    const int*   NNSites  = (const int*)d_in[11];    // (13,4096)
    const int*   S2Sh     = (const int*)d_in[12];    // (4096,)

    float* ws   = (float*)d_ws;
    float* GW0  = ws + OFF_GW0;
    float* GW1  = ws + OFF_GW1;
    float* GW2  = ws + OFF_GW2;
    float* Avc  = ws + OFF_AVC;
    float* A0   = ws + OFF_A0;
    float* A1   = ws + OFF_A1;
    float* A2   = ws + OFF_A2;
    float* PART = ws + OFF_PART;

    float* out = (float*)d_out;  // (64,3) f32

    // Avc is accumulated with atomics -> zero it (ws is poisoned 0xAA)
    hipMemsetAsync(Avc, 0, 39 * sizeof(float), stream);

    // rotated weights + collapsed vector-channel matrix (51792 threads)
    precompute_kernel<<<203, 256, 0, stream>>>(Psi0, Psi1, Psi2, wtVC, gdiags,
                                               GnnPerms, ws);

    // three gconv layers, register-tiled
    layer_tiled<1, 8, 12, 32, 8, 8, 64><<<BATCH * (SITES / 64), 256, 0, stream>>>(
        InStates, GW0, bias0, NNSites, A0);
    layer_tiled<8, 8, 12, 32, 8, 8, 64><<<BATCH * (SITES / 64), 256, 0, stream>>>(
        A0, GW1, bias1, NNSites, A1);
    layer_tiled<8, 1, 3, 16, 8, 16, 128><<<BATCH * (SITES / 128), 256, 0, stream>>>(
        A1, GW2, bias2, NNSites, A2);

    // vector channel + shell weighting + site mean (deterministic two-stage)
    reduce_a<<<BATCH * 16, 256, 0, stream>>>(A2, NNSites, S2Sh, ShellW, Avc, PART);
    reduce_b<<<1, 256, 0, stream>>>(PART, out);
}

// Round 4
// 775.207 us; speedup vs baseline: 2.0035x; 1.9302x over previous
//
#include <hip/hip_runtime.h>
#include <hip/hip_bf16.h>

// Problem constants (SymNetDP): B=64, S=4096, NGB=13, NG=48, DIM=3, NCH={8,8,1}
#define BATCH 64
#define SITES 4096
#define NGB 13
#define NGRP 48
#define SDIM 3

// ---------------------------------------------------------------------------
// Workspace layout (floats):
//   GW0 : (8,48,13)     =  4992   @ 0
//   GW1 : (8,48,104)    = 39936   @ 4992
//   GW2 : (48,104)      =  4992   @ 44928
//   Avc : (3,13)        =    39   @ 49920  (padded to 49984)
//   A0  : (B,8,S)       = 2097152 @ 49984
//   A1  : (B,8,S)       = 2097152 @ 2147136
//   A2  : (B,1,S)       =  262144 @ 4244288
//   PART: (64,16,3)     =  3072   @ 4506432
// ---------------------------------------------------------------------------
#define OFF_GW0 0
#define OFF_GW1 4992
#define OFF_GW2 44928
#define OFF_AVC 49920
#define OFF_A0  49984
#define OFF_A1  2147136
#define OFF_A2  4244288
#define OFF_PART 4506432

__device__ __forceinline__ float softplus_f(float h) {
    // stable: max(h,0) + log(1+exp(-|h|))
    return fmaxf(h, 0.f) + __logf(1.f + __expf(-fabsf(h)));
}

// ---------------------------------------------------------------------------
// Precompute: rotated weights GW0/GW1/GW2; Avc via per-(d,n,g) threads with
// atomicAdd (Avc zeroed by hipMemsetAsync before this kernel).
// ---------------------------------------------------------------------------
__global__ __launch_bounds__(256) void precompute_kernel(
    const float* __restrict__ Psi0, const float* __restrict__ Psi1,
    const float* __restrict__ Psi2, const float* __restrict__ wtVC,
    const float* __restrict__ gdiags, const int* __restrict__ perms,
    float* __restrict__ ws)
{
    float* GW0 = ws + OFF_GW0;
    float* GW1 = ws + OFF_GW1;
    float* GW2 = ws + OFF_GW2;
    float* Avc = ws + OFF_AVC;
    int t = blockIdx.x * 256 + threadIdx.x;
    if (t < 4992) {
        int j = t % NGB; int og = t / NGB; int g = og % NGRP; int o = og / NGRP;
        GW0[t] = Psi0[o * NGB + perms[g * NGB + j]];
    } else if (t < 44928) {
        int u = t - 4992;
        int k = u % 104; int og = u / 104; int g = og % NGRP; int o = og / NGRP;
        int c = k / NGB; int j = k % NGB;
        GW1[u] = Psi1[(o * 8 + c) * NGB + perms[g * NGB + j]];
    } else if (t < 49920) {
        int u = t - 44928;
        int k = u % 104; int g = u / 104; int c = k / NGB; int j = k % NGB;
        GW2[u] = Psi2[c * NGB + perms[g * NGB + j]];
    } else if (t < 49920 + 39 * NGRP) {
        int t2 = t - 49920;            // t2 = u*48 + g
        int g = t2 % NGRP, u = t2 / NGRP;
        int d = u / NGB, n = u % NGB;
        const int row = g * SDIM + d;
        float s = 0.f;
        for (int k = 0; k < NGRP * SDIM; k++) {
            int g2 = k / SDIM, d2 = k - g2 * SDIM;
            float p = wtVC[d2 * NGB + perms[g2 * NGB + n]];
            s = fmaf(gdiags[row * (NGRP * SDIM) + k], p, s);
        }
        atomicAdd(&Avc[u], s * (1.f / 48.f));
    }
}

// ---------------------------------------------------------------------------
// Register-tiled gconv layer, output-channel-split across blocks.
// Block handles NCB output channels (OG = NCB*48 rows) x CT columns.
// Thread owns TO rows x TC cols (TO*TC accumulators; keep <= 48 -> no spill).
// NO min-occupancy launch bound: round-3's (256,3) forced an 84-VGPR cap and
// spilled the accumulator tile to scratch (3.4 GB HBM writes / dispatch).
// ---------------------------------------------------------------------------
template<int NCIN, int NCTOT, int NCB, int TO, int GOG, int TC, int GCOL, int CT>
__global__ __launch_bounds__(256) void layer_tiled(
    const float* __restrict__ prev,   // (B, NCIN, S)
    const float* __restrict__ GW,     // (NCTOT*48, NCIN*13) row-major
    const float* __restrict__ bias,   // (NCTOT,)
    const int*   __restrict__ NN,     // (13, S)
    float* __restrict__ out)          // (B, NCTOT, S)
{
    constexpr int OG   = NCB * NGRP;       // rows handled by this block
    constexpr int K    = NCIN * NGB;
    constexpr int WSTR = OG + 4;           // padded row stride (16B-aligned)
    constexpr int PSTR = CT + 1;
    constexpr int WSZ  = (NGB * WSTR > GOG * PSTR) ? NGB * WSTR : GOG * PSTR;
    constexpr int GPO  = NGRP / TO;        // thread-groups per output channel
    constexpr int OSPL = NCTOT / NCB;

    static_assert(GOG * GCOL == 256, "");
    static_assert(TO * GOG == OG, "");
    static_assert(TC * GCOL == CT, "");
    static_assert(NGRP % TO == 0, "");     // thread's rows stay in one o

    __shared__ int   nn_lds[NGB * CT];
    __shared__ float x_lds[K * CT];        // [k][col]
    __shared__ float w_lds[WSZ];           // [j][og] chunk; reused for partials

    const int tid = threadIdx.x;
    const int og_group  = tid % GOG;
    const int col_group = tid / GOG;
    const int og0  = og_group * TO;
    const int col0 = col_group * TC;

    const int oblk = blockIdx.x % OSPL;
    const int bs   = blockIdx.x / OSPL;
    const int b    = bs / (SITES / CT);
    const int s0   = (bs % (SITES / CT)) * CT;

    const float* GWb = GW + (size_t)(oblk * OG) * K;

    // --- stage nn tile -----------------------------------------------------
    for (int e = tid; e < NGB * CT; e += 256) {
        int j = e / CT, col = e - j * CT;
        nn_lds[e] = NN[j * SITES + s0 + col];
    }
    __syncthreads();
    // --- stage gathered x tile, transposed [k][col] ------------------------
    for (int e = tid; e < K * CT; e += 256) {
        int k = e / CT, col = e - k * CT;
        int c = k / NGB, j = k - c * NGB;
        x_lds[e] = prev[((size_t)b * NCIN + c) * SITES + nn_lds[j * CT + col]];
    }

    const int o_local = og0 / NGRP;                     // within block
    const float bo = bias[oblk * NCB + o_local];
    float h[TO][TC];
#pragma unroll
    for (int i = 0; i < TO; i++)
#pragma unroll
        for (int q = 0; q < TC; q++) h[i][q] = bo;

    // --- K loop in channel chunks of 13 ------------------------------------
#pragma unroll 1
    for (int c = 0; c < NCIN; c++) {
        __syncthreads();   // (also covers x/nn staging before first compute)
        for (int e = tid; e < OG * NGB; e += 256) {
            int og = e / NGB, j = e - og * NGB;
            w_lds[j * WSTR + og] = GWb[(size_t)og * K + c * NGB + j];
        }
        __syncthreads();
        const float* xc = &x_lds[c * NGB * CT];
#pragma unroll
        for (int j = 0; j < NGB; j++) {
            float wv[TO], xv[TC];
#pragma unroll
            for (int i = 0; i < TO; i++) wv[i] = w_lds[j * WSTR + og0 + i];
#pragma unroll
            for (int q = 0; q < TC; q++) xv[q] = xc[j * CT + col0 + q];
#pragma unroll
            for (int i = 0; i < TO; i++)
#pragma unroll
                for (int q = 0; q < TC; q++)
                    h[i][q] = fmaf(wv[i], xv[q], h[i][q]);
        }
    }

    // --- epilogue: softplus, partial row-sum, group-mean --------------------
    float sp[TC];
#pragma unroll
    for (int q = 0; q < TC; q++) {
        float s = 0.f;
#pragma unroll
        for (int i = 0; i < TO; i++) s += softplus_f(h[i][q]);
        sp[q] = s;
    }
    __syncthreads();                        // done reading w_lds as weights
    float* part = w_lds;                    // [og_group][PSTR]
#pragma unroll
    for (int q = 0; q < TC; q++) part[og_group * PSTR + col0 + q] = sp[q];
    __syncthreads();
    for (int e = tid; e < NCB * CT; e += 256) {
        int oo = e / CT, col = e - oo * CT;
        float s = 0.f;
#pragma unroll
        for (int r = 0; r < GPO; r++) s += part[(oo * GPO + r) * PSTR + col];
        out[((size_t)b * NCTOT + oblk * NCB + oo) * SITES + s0 + col] =
            s * (1.f / 48.f);
    }
}

// ---------------------------------------------------------------------------
// Reduce stage A: per (b, s-chunk) block -> 3 partial sums
// ---------------------------------------------------------------------------
__global__ __launch_bounds__(256) void reduce_a(
    const float* __restrict__ A2,     // (B, S)
    const int*   __restrict__ NN,     // (13, S)
    const int*   __restrict__ s2sh,   // (S,)
    const float* __restrict__ sw,     // (NSHELLS,)
    const float* __restrict__ Avc,    // (3, 13)
    float* __restrict__ partial)      // (B, 16, 3)
{
    const int b = blockIdx.x >> 4;
    const int chunk = blockIdx.x & 15;
    const int tid = threadIdx.x;
    const int s = (chunk << 8) + tid;
    const float* a = A2 + (size_t)b * SITES;

    float y0 = 0.f, y1 = 0.f, y2 = 0.f;
#pragma unroll
    for (int n = 0; n < NGB; n++) {
        float v = a[NN[n * SITES + s]];
        y0 = fmaf(Avc[n],           v, y0);
        y1 = fmaf(Avc[NGB + n],     v, y1);
        y2 = fmaf(Avc[2 * NGB + n], v, y2);
    }
    const float wgt = sw[s2sh[s]];
    y0 *= wgt; y1 *= wgt; y2 *= wgt;

    __shared__ float red[3][256];
    red[0][tid] = y0; red[1][tid] = y1; red[2][tid] = y2;
    __syncthreads();
    for (int st = 128; st > 0; st >>= 1) {
        if (tid < st) {
            red[0][tid] += red[0][tid + st];
            red[1][tid] += red[1][tid + st];
            red[2][tid] += red[2][tid + st];
        }
        __syncthreads();
    }
    if (tid < 3) partial[(b * 16 + chunk) * 3 + tid] = red[tid][0];
}

__global__ __launch_bounds__(256) void reduce_b(
    const float* __restrict__ partial, float* __restrict__ out)
{
    int t = threadIdx.x;
    if (t < BATCH * 3) {
        int b = t / 3, d = t - b * 3;
        float s = 0.f;
        for (int c = 0; c < 16; c++) s += partial[(b * 16 + c) * 3 + d];
        out[t] = s * (1.f / (float)SITES);
    }
}

// ---------------------------------------------------------------------------
extern "C" void kernel_launch(void* const* d_in, const int* in_sizes, int n_in,
                              void* d_out, int out_size, void* d_ws, size_t ws_size,
                              hipStream_t stream)
{
    const float* InStates = (const float*)d_in[0];   // (64,1,4096)
    const float* Psi0     = (const float*)d_in[1];   // (8,1,13)
    const float* bias0    = (const float*)d_in[2];   // (8,1)
    const float* Psi1     = (const float*)d_in[3];   // (8,8,13)
    const float* bias1    = (const float*)d_in[4];   // (8,1)
    const float* Psi2     = (const float*)d_in[5];   // (1,8,13)
    const float* bias2    = (const float*)d_in[6];   // (1,1)
    const float* wtVC     = (const float*)d_in[7];   // (3,13)
    const float* ShellW   = (const float*)d_in[8];   // (8,)
    const float* gdiags   = (const float*)d_in[9];   // (144,144)
    const int*   GnnPerms = (const int*)d_in[10];    // (48,13)
    const int*   NNSites  = (const int*)d_in[11];    // (13,4096)
    const int*   S2Sh     = (const int*)d_in[12];    // (4096,)

    float* ws   = (float*)d_ws;
    float* GW0  = ws + OFF_GW0;
    float* GW1  = ws + OFF_GW1;
    float* GW2  = ws + OFF_GW2;
    float* Avc  = ws + OFF_AVC;
    float* A0   = ws + OFF_A0;
    float* A1   = ws + OFF_A1;
    float* A2   = ws + OFF_A2;
    float* PART = ws + OFF_PART;

    float* out = (float*)d_out;  // (64,3) f32

    hipMemsetAsync(Avc, 0, 39 * sizeof(float), stream);
    precompute_kernel<<<203, 256, 0, stream>>>(Psi0, Psi1, Psi2, wtVC, gdiags,
                                               GnnPerms, ws);

    // L0: NCIN=1, all 8 o in one block; CT=32, thread tile 12x4 = 48 accs
    layer_tiled<1, 8, 8, 12, 32, 4, 8, 32>
        <<<BATCH * (SITES / 32), 256, 0, stream>>>(InStates, GW0, bias0, NNSites, A0);
    // L1: NCIN=8, split o into 2 blocks of 4; CT=64, tile 6x8 = 48 accs
    layer_tiled<8, 8, 4, 6, 32, 8, 8, 64>
        <<<BATCH * (SITES / 64) * 2, 256, 0, stream>>>(A0, GW1, bias1, NNSites, A1);
    // L2: NCIN=8, NCOUT=1; CT=64, tile 3x4 = 12 accs
    layer_tiled<8, 1, 1, 3, 16, 4, 16, 64>
        <<<BATCH * (SITES / 64), 256, 0, stream>>>(A1, GW2, bias2, NNSites, A2);

    reduce_a<<<BATCH * 16, 256, 0, stream>>>(A2, NNSites, S2Sh, ShellW, Avc, PART);
    reduce_b<<<1, 256, 0, stream>>>(PART, out);
}